// Round 3
// baseline (39127.206 us; speedup 1.0000x reference)
//
#include <hip/hip_runtime.h>
#include <math.h>

#pragma clang fp contract(off)

#define NS 1024
#define NU 8192
#define FINF __builtin_huge_valf()

// ws layout (int units): [0] byteMode flag; [64..8255] order;
// [8256..41023] wl (floats, sorted workloads); [41024..303167] packed masks
#define WS_ORDER 64
#define WS_WL 8256
#define WS_PM 41024
#define WS_NEED_BYTES ((size_t)(WS_PM + NU * 32) * 4 + 256)

// ---------------------------------------------------------------------------
// Kernel 0: detect mask encoding. Words all in {0,1,0x3F800000} => 4-byte
// elements (int32 or float32). Anything else => 1-byte elements.
// ---------------------------------------------------------------------------
__global__ void detect_kernel(const unsigned* __restrict__ m, int* __restrict__ flag) {
    __shared__ int s_any;
    if (threadIdx.x == 0) s_any = 0;
    __syncthreads();
    int bad = 0;
    for (int i = threadIdx.x; i < 65536; i += 256) {
        unsigned v = m[i];
        bad |= !(v == 0u || v == 1u || v == 0x3F800000u);
    }
    if (bad) s_any = 1;   // benign same-value race
    __syncthreads();
    if (threadIdx.x == 0) flag[0] = s_any;
}

// ---------------------------------------------------------------------------
// Kernel 1: stable rank sort of users[:,2] -> order[rank] = i
// ---------------------------------------------------------------------------
__global__ void rank_kernel(const float* __restrict__ users, int* __restrict__ order) {
    __shared__ float keys[2048];
    const int i = blockIdx.x * 256 + threadIdx.x;
    const float key = users[i * 6 + 2];
    int rank = 0;
    for (int base = 0; base < NU; base += 2048) {
        __syncthreads();
        for (int k = threadIdx.x; k < 2048; k += 256)
            keys[k] = users[(base + k) * 6 + 2];
        __syncthreads();
        for (int k = 0; k < 2048; ++k) {
            float kj = keys[k];
            int j = base + k;
            rank += (kj < key) || ((kj == key) && (j < i));
        }
    }
    order[rank] = i;
}

// ---------------------------------------------------------------------------
// Kernel 1b: gather workloads in sorted order
// ---------------------------------------------------------------------------
__global__ void gather_kernel(const float* __restrict__ users, const int* __restrict__ order,
                              float* __restrict__ wl) {
    const int stp = blockIdx.x * 256 + threadIdx.x;
    const int u = order[stp];
    float2 a = *(const float2*)(users + u * 6 + 2);
    float2 b = *(const float2*)(users + u * 6 + 4);
    *(float4*)(wl + stp * 4) = make_float4(a.x, a.y, b.x, b.y);
}

// ---------------------------------------------------------------------------
// Kernel 1c: pack masks to 1 bit/server, in sorted user order.
// ---------------------------------------------------------------------------
__global__ void pack_kernel(const void* __restrict__ masksv, const int* __restrict__ wsi,
                            const int* __restrict__ order, unsigned* __restrict__ pm) {
    const int idx = blockIdx.x * 256 + threadIdx.x;
    const int stp = idx >> 5, w = idx & 31;
    const int u = order[stp];
    const int byteMode = wsi[0];
    unsigned word = 0;
    if (byteMode) {
        const uint4* q = (const uint4*)((const unsigned char*)masksv + (size_t)u * NS + w * 32);
        uint4 a = q[0], b = q[1];
        unsigned vv[8] = {a.x, a.y, a.z, a.w, b.x, b.y, b.z, b.w};
        #pragma unroll
        for (int d = 0; d < 8; ++d) {
            #pragma unroll
            for (int i = 0; i < 4; ++i)
                if ((vv[d] >> (8 * i)) & 0xFFu) word |= 1u << (d * 4 + i);
        }
    } else {
        const int4* q = (const int4*)((const int*)masksv + (size_t)u * NS + w * 32);
        #pragma unroll
        for (int d = 0; d < 8; ++d) {
            int4 v = q[d];
            if (v.x) word |= 1u << (d * 4 + 0);
            if (v.y) word |= 1u << (d * 4 + 1);
            if (v.z) word |= 1u << (d * 4 + 2);
            if (v.w) word |= 1u << (d * 4 + 3);
        }
    }
    pm[idx] = word;
}

// ---------------------------------------------------------------------------
// Kernel 2: sequential allocator. SINGLE WAVE: 64 lanes x 16 servers/lane.
// No barriers; all reductions are intra-wave shuffle butterflies.
// ---------------------------------------------------------------------------
template <bool PACKED>
__global__ __launch_bounds__(64, 1)
void alloc_kernel(const float* __restrict__ servers,
                  const float* __restrict__ users,
                  const void*  __restrict__ masksv,
                  const int*   __restrict__ wsi,
                  float* __restrict__ out) {
    const int lane  = threadIdx.x;
    const int sbase = lane * 16;
    const int byteMode = wsi[0];
    const int* __restrict__ order_g = wsi + WS_ORDER;
    const float* __restrict__ wlf = (const float*)(wsi + WS_WL);
    const unsigned* __restrict__ pm = (const unsigned*)(wsi + WS_PM);
    const unsigned char* __restrict__ mbytes = (const unsigned char*)masksv;
    const int*           __restrict__ mwords = (const int*)masksv;

    __shared__ float s_res[NU];
    __shared__ float s_cap[NS * 4];

    // per-lane state: servers sbase..sbase+15 (all static-indexed -> VGPRs)
    float t[16][4], f[16][4], B[16], us[16], fs[16];
    int virg = 0xFFFF;   // bit j set: us[j] == 0

    #pragma unroll
    for (int j = 0; j < 16; ++j) {
        #pragma unroll
        for (int k = 0; k < 4; ++k) {
            float cv = servers[(sbase + j) * 7 + 3 + k];
            t[j][k] = cv;
            f[j][k] = 0.0f;
            s_cap[(sbase + j) * 4 + k] = cv;
        }
        B[j] = 0.0f; us[j] = 0.0f; fs[j] = 0.0f;
    }

    auto step = [&](int stp, unsigned vm, float4 wl) {
        const float w0 = wl.x, w1 = wl.y, w2 = wl.z, w3 = wl.w;

        // ---- phase A: valid bits, sum(fuzzy), minmax(B)
        int vbits = 0;
        float sumF = 0.0f, mxB = -FINF, mnB = FINF;
        #pragma unroll
        for (int j = 0; j < 16; ++j) {
            bool ok = ((vm >> j) & 1u) &&
                      (t[j][0] >= w0) && (t[j][1] >= w1) &&
                      (t[j][2] >= w2) && (t[j][3] >= w3);
            if (ok) {
                vbits |= 1 << j;
                sumF += fs[j];
                mxB = fmaxf(mxB, B[j]);
                mnB = fminf(mnB, B[j]);
            }
        }
        float cnt = (float)__popc(vbits);
        #pragma unroll
        for (int off = 1; off <= 32; off <<= 1) {
            sumF += __shfl_xor(sumF, off);
            cnt  += __shfl_xor(cnt, off);
            mxB = fmaxf(mxB, __shfl_xor(mxB, off));
            mnB = fminf(mnB, __shfl_xor(mnB, off));
        }
        bool hasC10 = __ballot((vbits & virg) != 0) != 0ULL;
        bool hasC0  = __ballot((vbits & ~virg) != 0) != 0ULL;

        if (cnt > 0.0f) {
            // ---- variance (two-pass, same per-element order as reference path)
            float n = cnt * 4.0f;
            float mean = sumF / fmaxf(n, 1.0f);
            float s2 = 0.0f;
            #pragma unroll
            for (int j = 0; j < 16; ++j) {
                if ((vbits >> j) & 1) {
                    float d0 = f[j][0] - mean;
                    float d1 = f[j][1] - mean;
                    float d2 = f[j][2] - mean;
                    float d3 = f[j][3] - mean;
                    s2 += d0 * d0 + d1 * d1 + d2 * d2 + d3 * d3;
                }
            }
            #pragma unroll
            for (int off = 1; off <= 32; off <<= 1) s2 += __shfl_xor(s2, off);
            float var = s2 / fmaxf(n - 1.0f, 1.0f);
            float sd  = sqrtf(var);
            int row = (mean <= 0.2f) ? 0 : ((mean <= 0.5f) ? 1 : 2);
            int col = (sd   <= 0.1f) ? 0 : ((sd   <= 0.3f) ? 1 : 2);
            float r0 = (col == 0) ? 0.9f : ((col == 1) ? 0.8f : 0.6f);
            float r1 = (col == 0) ? 0.6f : ((col == 1) ? 0.5f : 0.4f);
            float r2 = (col == 0) ? 0.4f : ((col == 1) ? 0.2f : 0.1f);
            float tw = (row == 0) ? r0 : ((row == 1) ? r1 : r2);

            float mxC = hasC10 ? 10.0f : 0.0f;
            float mnC = hasC0  ? 0.0f  : 10.0f;
            float dB = mxB - mnB;
            float dC = mxC - mnC;
            float ci10 = (dC != 0.0f) ? (10.0f - mnC) / dC : 0.0f;
            float ci0  = (dC != 0.0f) ? (0.0f  - mnC) / dC : 0.0f;
            float a  = tw + 0.3f;
            float bb = (1.0f - tw) + 0.55f;
            float b10 = bb * ci10, b0v = bb * ci0;

            // ---- scores + argmin
            float bV = FINF; int bI = NS;
            #pragma unroll
            for (int j = 0; j < 16; ++j) {
                float bi = (dB != 0.0f) ? (B[j] - mnB) / dB : 0.0f;
                float sc = a * bi + (((virg >> j) & 1) ? b10 : b0v);
                float key = ((vbits >> j) & 1) ? sc : FINF;
                if (key < bV) { bV = key; bI = sbase + j; }   // ascending j: first wins ties
            }
            #pragma unroll
            for (int off = 1; off <= 32; off <<= 1) {
                float ov = __shfl_xor(bV, off);
                int   oi = __shfl_xor(bI, off);
                if (ov < bV || (ov == bV && oi < bI)) { bV = ov; bI = oi; }
            }
            const int chosen = __builtin_amdgcn_readfirstlane(bI);
            if (lane == 0) s_res[stp] = (float)chosen;

            // ---- update chosen server (winner lane, static register indexing)
            const int wj = chosen & 15;
            if ((chosen >> 4) == lane) {
                float4 cv4 = *(float4*)&s_cap[chosen * 4];
                float cc[4] = {cv4.x, cv4.y, cv4.z, cv4.w};
                #pragma unroll
                for (int j = 0; j < 16; ++j) {
                    if (wj == j) {    // uniform (SGPR) -> scalar branch
                        t[j][0] = t[j][0] - w0;
                        t[j][1] = t[j][1] - w1;
                        t[j][2] = t[j][2] - w2;
                        t[j][3] = t[j][3] - w3;
                        us[j] = us[j] + 1.0f;
                        virg &= ~(1 << j);
                        #pragma unroll
                        for (int k = 0; k < 4; ++k) {
                            const float mid  = (k == 0) ? 0.4f : ((k == 1) ? 0.5f : ((k == 2) ? 0.3f : 0.5f));
                            const float high = (k == 0) ? 0.8f : ((k == 1) ? 0.8f : ((k == 2) ? 0.7f : 0.8f));
                            float rem = cc[k] - t[j][k];
                            float x = rem / cc[k];
                            float fv;
                            if (x <= 0.0f)      fv = 0.0f;
                            else if (x <= mid)  fv = x / mid;
                            else if (x <= high) fv = (high - x) / (high - mid);
                            else                fv = 0.0f;
                            f[j][k] = fv;
                        }
                        fs[j] = ((f[j][0] + f[j][1]) + f[j][2]) + f[j][3];
                        float sB = ((t[j][0] / cc[0] + t[j][1] / cc[1]) + t[j][2] / cc[2]) + t[j][3] / cc[3];
                        B[j] = 1.0f - sB * 0.25f;
                    }
                }
            }
        } else {
            if (lane == 0) s_res[stp] = -1.0f;
        }
    };

    if (PACKED) {
        auto load_pm = [&](int stp) -> unsigned { return pm[stp * 32 + (lane >> 1)]; };
        auto load_wl = [&](int stp) -> float4  { return *(const float4*)(wlf + stp * 4); };
        const int sh = (lane & 1) * 16;
        unsigned mA = load_pm(0), mB = load_pm(1);
        float4  wA = load_wl(0),  wB = load_wl(1);
        for (int p = 0; p < NU / 2; ++p) {
            unsigned m0 = mA; float4 q0 = wA;
            if (2 * p + 2 < NU) { mA = load_pm(2 * p + 2); wA = load_wl(2 * p + 2); }
            step(2 * p, (m0 >> sh) & 0xFFFFu, q0);
            unsigned m1 = mB; float4 q1 = wB;
            if (2 * p + 3 < NU) { mB = load_pm(2 * p + 3); wB = load_wl(2 * p + 3); }
            step(2 * p + 1, (m1 >> sh) & 0xFFFFu, q1);
        }
    } else {
        for (int stp = 0; stp < NU; ++stp) {
            int u = order_g[stp];
            unsigned vm = 0;
            if (byteMode) {
                uint4 a = *(const uint4*)(mbytes + (size_t)u * NS + sbase);
                unsigned d[4] = {a.x, a.y, a.z, a.w};
                #pragma unroll
                for (int di = 0; di < 4; ++di)
                    #pragma unroll
                    for (int bi = 0; bi < 4; ++bi)
                        if ((d[di] >> (8 * bi)) & 0xFFu) vm |= 1u << (di * 4 + bi);
            } else {
                #pragma unroll
                for (int di = 0; di < 4; ++di) {
                    int4 v = *(const int4*)(mwords + (size_t)u * NS + sbase + di * 4);
                    if (v.x) vm |= 1u << (di * 4 + 0);
                    if (v.y) vm |= 1u << (di * 4 + 1);
                    if (v.z) vm |= 1u << (di * 4 + 2);
                    if (v.w) vm |= 1u << (di * 4 + 3);
                }
            }
            float2 a2 = *(const float2*)(users + u * 6 + 2);
            float2 b2 = *(const float2*)(users + u * 6 + 4);
            step(stp, vm, make_float4(a2.x, a2.y, b2.x, b2.y));
        }
    }

    // ---- epilogue: write allocations (scatter by order), usage, proportions
    float ac = 0.0f;
    for (int i = lane; i < NU; i += 64) {
        float v = s_res[i];
        out[order_g[i]] = v;
        ac += (v != -1.0f) ? 1.0f : 0.0f;
    }
    float uc = 0.0f;
    #pragma unroll
    for (int j = 0; j < 16; ++j) {
        out[NU + sbase + j] = us[j];
        uc += (us[j] != 0.0f) ? 1.0f : 0.0f;
    }
    #pragma unroll
    for (int off = 1; off <= 32; off <<= 1) {
        ac += __shfl_xor(ac, off);
        uc += __shfl_xor(uc, off);
    }
    if (lane == 0) {
        out[NU + NS]     = ac / 8192.0f;
        out[NU + NS + 1] = uc / 1024.0f;
    }
}

// ---------------------------------------------------------------------------
extern "C" void kernel_launch(void* const* d_in, const int* in_sizes, int n_in,
                              void* d_out, int out_size, void* d_ws, size_t ws_size,
                              hipStream_t stream) {
    const float* servers = (const float*)d_in[0];
    const float* users   = (const float*)d_in[1];
    const void*  masks   = d_in[2];
    int*   wsi = (int*)d_ws;
    float* out = (float*)d_out;

    detect_kernel<<<1, 256, 0, stream>>>((const unsigned*)masks, wsi);
    rank_kernel<<<32, 256, 0, stream>>>(users, wsi + WS_ORDER);
    if (ws_size >= WS_NEED_BYTES) {
        gather_kernel<<<NU / 256, 256, 0, stream>>>(users, wsi + WS_ORDER, (float*)(wsi + WS_WL));
        pack_kernel<<<NU * 32 / 256, 256, 0, stream>>>(masks, wsi, wsi + WS_ORDER,
                                                       (unsigned*)(wsi + WS_PM));
        alloc_kernel<true><<<1, 64, 0, stream>>>(servers, users, masks, wsi, out);
    } else {
        alloc_kernel<false><<<1, 64, 0, stream>>>(servers, users, masks, wsi, out);
    }
}